// Round 4
// baseline (466.489 us; speedup 1.0000x reference)
//
#include <hip/hip_runtime.h>
#include <hip/hip_bf16.h>
#include <stdint.h>

// Problem constants (fixed by reference setup_inputs)
#define NX 16384   // rows of x
#define NC 4096    // rows of prototype (= output cols)
#define DIM 1024   // feature dim (K)

typedef __attribute__((ext_vector_type(8))) short bf16x8;   // 8 bf16 = 4 VGPRs
typedef __attribute__((ext_vector_type(4))) float f32x4;

// ---------- helpers ----------

__device__ inline unsigned short f2bf_rn(float f) {
  union { float f; unsigned u; } v; v.f = f;
  unsigned u = v.u;
  unsigned r = (u + 0x7FFFu + ((u >> 16) & 1u)) >> 16;  // round-nearest-even
  return (unsigned short)r;
}

__device__ inline void gload_lds16(const void* g, void* l) {
  // width-16 direct global->LDS. LDS dest = wave-uniform base + lane*16 (linear).
  __builtin_amdgcn_global_load_lds(
      (const __attribute__((address_space(1))) void*)g,
      (__attribute__((address_space(3))) void*)l,
      16, 0, 0);
}

__device__ inline f32x4 mfma_bf16_16x16x32(bf16x8 a, bf16x8 b, f32x4 c) {
  asm("v_mfma_f32_16x16x32_bf16 %0, %1, %2, %0" : "+v"(c) : "v"(a), "v"(b));
  return c;
}

// ---------- kernel 1: fused fp32 -> bf16 + fp32 row sum-of-squares ----------
// one wave per row; 4 waves/block; rows = NX (x) then NC (prototype).

__global__ __launch_bounds__(256) void convert_all(
    const float* __restrict__ x, const float* __restrict__ p,
    unsigned short* __restrict__ xb, unsigned short* __restrict__ pb,
    float* __restrict__ xsq, float* __restrict__ psq) {
  const int gw = blockIdx.x * 4 + (threadIdx.x >> 6);
  const int lane = threadIdx.x & 63;
  const float* src; unsigned short* dst; float* sq; int row;
  if (gw < NX) { src = x; dst = xb; sq = xsq; row = gw; }
  else         { src = p; dst = pb; sq = psq; row = gw - NX; }
  const size_t base = (size_t)row * DIM;

  float s = 0.f;
  #pragma unroll
  for (int j = 0; j < 4; ++j) {
    const float4 v = *(const float4*)(src + base + j * 256 + lane * 4);
    s += v.x * v.x + v.y * v.y + v.z * v.z + v.w * v.w;
    ushort4 o;
    o.x = f2bf_rn(v.x); o.y = f2bf_rn(v.y);
    o.z = f2bf_rn(v.z); o.w = f2bf_rn(v.w);
    *(ushort4*)(dst + base + j * 256 + lane * 4) = o;
  }
  #pragma unroll
  for (int off = 32; off; off >>= 1) s += __shfl_xor(s, off, 64);
  if (lane == 0) sq[row] = s;
}

// ---------- kernel 2: 8-phase 256x128 bf16 MFMA GEMM + distance epilogue ----
// BM=256, BN=128, BK=64. 512 thr = 8 waves (4M x 2N), wave tile 64x64 =
// acc[4][4]. Per K-tile: 2 phases x {8 ds_read_b128 || 3 gload_lds ->
// barrier -> setprio(1) 16 MFMA setprio(0) -> barrier}. 3-buffer LDS ring
// (48KB/tile, 144KB total), prefetch distance 2, counted vmcnt(6) once per
// K-tile (never 0 in main loop). T2 swizzle = st_16x32:
//   physical = logical ^ (((logical>>9)&1)<<5)   (involution)
// write side: gload_lds dest LINEAR, per-lane global SOURCE pre-swizzled;
// read side: ds_read at swizzled address.

#define BM 256
#define BN 128
#define BK 64
#define NT (DIM / BK)       // 16
#define LBUF 49152          // A: 32KB [256][64]bf16  +  B: 16KB [128][64]bf16

__global__ __launch_bounds__(512, 2) void dist_gemm(
    const unsigned short* __restrict__ xb,   // [NX][DIM] bf16
    const unsigned short* __restrict__ pb,   // [NC][DIM] bf16
    const float* __restrict__ xsq,           // [NX]
    const float* __restrict__ psq,           // [NC]
    float* __restrict__ out) {               // [NX][NC]
  extern __shared__ char lds[];   // 147456 B = 3 x LBUF

  const int tid  = threadIdx.x;
  const int wid  = tid >> 6;      // 0..7
  const int lane = tid & 63;
  const int wm = wid >> 1;        // 0..3 (64-row slice of BM)
  const int wn = wid & 1;         // 0..1 (64-col slice of BN)

  // T1: bijective XCD supertile map. 2048 wgs = 8 XCDs x 256. Each XCD owns
  // an 8-row stripe of tm; tn sweeps fastest -> consecutive blocks share A.
  const int bid = blockIdx.x;
  const int xcd = bid & 7;
  const int idx = bid >> 3;                 // 0..255
  const int tm  = xcd * 8 + (idx >> 5);     // 0..63
  const int tn  = idx & 31;                 // 0..31
  const int row0 = tm * BM, col0 = tn * BN;

  // --- staging (write side) ---
  // dest byte d (linear) = step*8192 + wid*1024 + lane*16
  //   -> logical row = d>>7 = step*64 + wid*8 + (lane>>3)   (bit9 is row bit2)
  //   -> logical colbyte = (lane&7)*16 ^ (((lane>>5)&1)<<5)  (pre-swizzled src)
  const int srow = wid * 8 + (lane >> 3);   // + step*64
  const int scb  = (((lane & 7) ^ (((lane >> 5) & 1) << 1)) << 4);
  const char* gA = (const char*)xb + (size_t)(row0 + srow) * (DIM * 2) + scb;
  const char* gB = (const char*)pb + (size_t)(col0 + srow) * (DIM * 2) + scb;
  // step stride in global bytes: 64 rows * 2048 B = 131072

  // --- read side (swizzled ds_read) ---
  // frag(m|n, ks): logical row = base + 16*m + (lane&15), colbyte = ks*64 +
  // (lane>>4)*16; physical colbyte ^= ((row>>2)&1)<<5 = ((lane>>2)&1)<<5.
  const int fr  = lane & 15;
  const int rsw = (lane & 4) << 3;               // bit5 flip from row bit2
  const int g16 = (lane >> 4) << 4;
  const int aro = (wm * 64 + fr) * 128;          // + m*2048, within A region
  const int bro = (wn * 64 + fr) * 128 + 32768;  // + n*2048, within B region
  const int c0  = g16 ^ rsw;                     // ks=0 colbyte (phys)
  const int c1  = 64 + (g16 ^ rsw);              // ks=1 (bit6 untouched by swz)

  f32x4 acc[4][4] = {};

  char* p0 = lds;                 // compute buffer (tile t)
  char* p1 = lds + LBUF;          // tile t+1
  char* p2 = lds + 2 * LBUF;      // staging dest (tile t+2)

#define STAGE_A012(kt, dst) do {                                        \
    const size_t ko = (size_t)(kt) * 128;                               \
    gload_lds16(gA + ko,          (dst) + wid * 1024);                  \
    gload_lds16(gA + ko + 131072, (dst) + 8192  + wid * 1024);          \
    gload_lds16(gA + ko + 262144, (dst) + 16384 + wid * 1024);          \
  } while (0)
#define STAGE_A3B01(kt, dst) do {                                       \
    const size_t ko = (size_t)(kt) * 128;                               \
    gload_lds16(gA + ko + 393216, (dst) + 24576 + wid * 1024);          \
    gload_lds16(gB + ko,          (dst) + 32768 + wid * 1024);          \
    gload_lds16(gB + ko + 131072, (dst) + 40960 + wid * 1024);          \
  } while (0)

  // prologue: stage tiles 0 and 1 (12 loads), wait for tile 0 only
  STAGE_A012(0, p0); STAGE_A3B01(0, p0);
  STAGE_A012(1, p1); STAGE_A3B01(1, p1);
  asm volatile("s_waitcnt vmcnt(6)" ::: "memory");
  __builtin_amdgcn_s_barrier();
  asm volatile("" ::: "memory");

  for (int t = 0; t < NT; ++t) {
    const bool more = (t < NT - 2);

    // ---- phase 1: ks=0 ----
    bf16x8 a0[4], b0[4];
    #pragma unroll
    for (int m = 0; m < 4; ++m) a0[m] = *(const bf16x8*)(p0 + aro + m * 2048 + c0);
    #pragma unroll
    for (int n = 0; n < 4; ++n) b0[n] = *(const bf16x8*)(p0 + bro + n * 2048 + c0);
    if (more) STAGE_A012(t + 2, p2);
    asm volatile("" ::: "memory");
    __builtin_amdgcn_s_barrier();
    asm volatile("" ::: "memory");
    __builtin_amdgcn_s_setprio(1);
    #pragma unroll
    for (int m = 0; m < 4; ++m)
      #pragma unroll
      for (int n = 0; n < 4; ++n)
        acc[m][n] = mfma_bf16_16x16x32(a0[m], b0[n], acc[m][n]);
    __builtin_amdgcn_s_setprio(0);
    asm volatile("" ::: "memory");
    __builtin_amdgcn_s_barrier();
    asm volatile("" ::: "memory");

    // ---- phase 2: ks=1 ----
    bf16x8 a1[4], b1[4];
    #pragma unroll
    for (int m = 0; m < 4; ++m) a1[m] = *(const bf16x8*)(p0 + aro + m * 2048 + c1);
    #pragma unroll
    for (int n = 0; n < 4; ++n) b1[n] = *(const bf16x8*)(p0 + bro + n * 2048 + c1);
    if (more) STAGE_A3B01(t + 2, p2);
    asm volatile("" ::: "memory");
    __builtin_amdgcn_s_barrier();
    asm volatile("" ::: "memory");
    __builtin_amdgcn_s_setprio(1);
    #pragma unroll
    for (int m = 0; m < 4; ++m)
      #pragma unroll
      for (int n = 0; n < 4; ++n)
        acc[m][n] = mfma_bf16_16x16x32(a1[m], b1[n], acc[m][n]);
    __builtin_amdgcn_s_setprio(0);
    // counted wait: 12 outstanding (t+1's 6 + t+2's 6) -> drain t+1's only.
    if (more)            asm volatile("s_waitcnt vmcnt(6)" ::: "memory");
    else if (t == NT - 2) asm volatile("s_waitcnt vmcnt(0)" ::: "memory");
    asm volatile("" ::: "memory");
    __builtin_amdgcn_s_barrier();
    asm volatile("" ::: "memory");

    // rotate ring: t+1 becomes compute, old compute becomes stage dest
    char* tmp = p0; p0 = p1; p1 = p2; p2 = tmp;
  }

#undef STAGE_A012
#undef STAGE_A3B01

  // epilogue: d = xsq[r] + psq[c] - 2*cross
  // C/D layout (m89): col = lane&15, row = (lane>>4)*4 + reg.
  const int orow = row0 + wm * 64 + ((lane >> 4) << 2);
  const int ocol = col0 + wn * 64 + fr;
  float pv[4];
  #pragma unroll
  for (int n = 0; n < 4; ++n) pv[n] = psq[ocol + n * 16];

  #pragma unroll
  for (int m = 0; m < 4; ++m) {
    #pragma unroll
    for (int ri = 0; ri < 4; ++ri) {
      const int r = orow + m * 16 + ri;
      const float xv = xsq[r];
      #pragma unroll
      for (int n = 0; n < 4; ++n)
        out[(size_t)r * NC + ocol + n * 16] = xv + pv[n] - 2.0f * acc[m][n][ri];
    }
  }
}

// ---------- launch ----------

extern "C" void kernel_launch(void* const* d_in, const int* in_sizes, int n_in,
                              void* d_out, int out_size, void* d_ws, size_t ws_size,
                              hipStream_t stream) {
  const float* x = (const float*)d_in[0];   // [16384][1024] fp32
  const float* p = (const float*)d_in[1];   // [4096][1024] fp32
  float* out = (float*)d_out;               // [16384][4096] fp32

  // workspace layout (40.1 MB total)
  char* ws = (char*)d_ws;
  unsigned short* xb  = (unsigned short*)ws;                          // 32 MB
  unsigned short* pbb = (unsigned short*)(ws + (size_t)NX * DIM * 2); // 8 MB
  float* xsq = (float*)(ws + (size_t)NX * DIM * 2 + (size_t)NC * DIM * 2);
  float* psq = xsq + NX;

  convert_all<<<(NX + NC) / 4, 256, 0, stream>>>(x, p, xb, pbb, xsq, psq);

  // 144 KB dynamic LDS needs explicit opt-in (gfx950 GROUP segment = 160 KB)
  (void)hipFuncSetAttribute((const void*)dist_gemm,
                            hipFuncAttributeMaxDynamicSharedMemorySize,
                            3 * LBUF);

  dim3 grid((NX / BM) * (NC / BN));   // 64 * 32 = 2048, % 8 == 0 (bijective)
  dist_gemm<<<grid, dim3(512), 3 * LBUF, stream>>>(xb, pbb, xsq, psq, out);
}